// Round 6
// baseline (1118.692 us; speedup 1.0000x reference)
//
#include <hip/hip_runtime.h>
#include <cstdint>
#include <cmath>

#define N_ATOMS 65536
#define N_BONDS 98304
#define N_MOLS  4096
#define D_IN    128
#define DD      256
#define REPEAT  3

typedef __attribute__((ext_vector_type(8))) short short8;   // 8 f16 = 4 VGPR
typedef __attribute__((ext_vector_type(4))) float f32x4;
typedef unsigned short ushort_t;

__device__ __forceinline__ unsigned short f2h(float f) {    // RNE f32->f16
  union { _Float16 h; unsigned short u; } x; x.h = (_Float16)f; return x.u;
}
__device__ __forceinline__ float h2f(unsigned short u) {
  union { unsigned short u; _Float16 h; } x; x.u = u; return (float)x.h;
}

#define GLD16(gp, lp) __builtin_amdgcn_global_load_lds( \
    (const __attribute__((address_space(1))) void*)(gp), \
    (__attribute__((address_space(3))) void*)(lp), 16, 0, 0)

// ---------------------------------------------------------------------------
// MFMA concat-gather GEMM + tanh (fp16 in, f32 acc, fp16 out [+f32 out]).
// R6: (1) A-tile in fragment-major LDS layout -> every ds_read_b128 is
// lane-linear over 1024 contiguous bytes = conflict-free, no swizzle.
// (2) B (weights) skips LDS: pre-transformed fragment-major PreW in global
// (L2-resident), loaded per K-step as coalesced 1024B global_load_dwordx4.
// Double-buffered A, one barrier per K-step. Full-N blocks -> in-place safe.
//   PreW chunk layout: byte = ((g*KTOT + kt)*1024) + (l>>4)*256 + (l&15)*16
//   holding W[k = kt*32 + (l>>4)*8 + j][col = 16g + (l&15)], j=0..7.
// ---------------------------------------------------------------------------
template<int NSEG, int SEGW, int BM>
__global__ __launch_bounds__(BM * 4)
void mfma_concat_gemm(const ushort_t* __restrict__ s0, const int* __restrict__ i0,
                      const ushort_t* __restrict__ s1, const int* __restrict__ i1,
                      const ushort_t* __restrict__ s2, const int* __restrict__ i2,
                      const ushort_t* __restrict__ s3, const int* __restrict__ i3,
                      const ushort_t* __restrict__ s4, const int* __restrict__ i4,
                      const ushort_t* __restrict__ PreW,
                      ushort_t* __restrict__ ob, ushort_t* __restrict__ ob2,
                      float* __restrict__ of)
{
  constexpr int NT     = BM * 4;            // threads
  constexpr int KW     = NSEG * SEGW;       // total K
  constexpr int KTOT   = KW / 32;           // total K-steps
  constexpr int SPS    = SEGW / 32;         // K-steps per segment
  constexpr int ABYTES = BM * 64;           // A tile bytes (= NT*16)

  __shared__ __align__(16) char smem[2 * ABYTES];

  const int t  = threadIdx.x;
  const int m0 = blockIdx.x * BM;

  // A staging: thread t owns (row ra, 16B k-chunk kca) in fragment-major slot t*16
  const int ra  = ((t >> 6) << 4) + (t & 15);
  const int kca = (t >> 4) & 3;

  // per-thread gathered A-row pointers (kca folded in), one per segment
  const char* arows[5];
  {
    const int rg = m0 + ra;
    const int* ips[5] = { i0, i1, i2, i3, i4 };
    const ushort_t* sps[5] = { s0, s1, s2, s3, s4 };
    #pragma unroll
    for (int s = 0; s < NSEG; ++s) {
      int idx = ips[s] ? ips[s][rg] : rg;
      arows[s] = (const char*)sps[s] + (size_t)idx * (SEGW * 2) + kca * 16;
    }
  }

  f32x4 acc[4][4];
  const f32x4 z = {0.f, 0.f, 0.f, 0.f};
  #pragma unroll
  for (int a = 0; a < 4; ++a)
    #pragma unroll
    for (int b = 0; b < 4; ++b) acc[a][b] = z;

  const int l   = t & 63;
  const int wid = t >> 6;
  const int wr  = wid >> 2;                 // 0..BM/64-1 (row strip of 64)
  const int wc  = wid & 3;                  // 0..3 (col strip of 64)
  const int aro = wr * 4096 + l * 16;       // + mf*1024 : lane-linear reads
  const char* pwb = (const char*)PreW + ((size_t)(wc * 4) * KTOT) * 1024 + l * 16;

  auto stage_tile = [&](int segS, int sub, int db) {
    GLD16(arows[segS] + sub * 64, smem + db + t * 16);
  };
  auto compute = [&](int sb, int kt) {
    short8 bfv[4];
    #pragma unroll
    for (int nf = 0; nf < 4; ++nf)
      bfv[nf] = *(const short8*)(pwb + (size_t)((nf * KTOT + kt) << 10));
    short8 af[4];
    #pragma unroll
    for (int mf = 0; mf < 4; ++mf)
      af[mf] = *(const short8*)(smem + sb + aro + mf * 1024);
    #pragma unroll
    for (int mf = 0; mf < 4; ++mf)
      #pragma unroll
      for (int nf = 0; nf < 4; ++nf)
        acc[mf][nf] = __builtin_amdgcn_mfma_f32_16x16x32_f16(af[mf], bfv[nf], acc[mf][nf], 0, 0, 0);
  };

  // prologue: stage first A tile into buffer 0
  stage_tile(0, 0, 0);
  __syncthreads();

  int cur = 0;
  #pragma unroll
  for (int seg = 0; seg < NSEG; ++seg) {
    for (int sub = 0; sub < SPS; ++sub) {
      const int nb = (cur ^ 1) * ABYTES;
      if (sub + 1 < SPS)       stage_tile(seg, sub + 1, nb);   // same seg (static)
      else if (seg + 1 < NSEG) stage_tile(seg + 1, 0, nb);     // next seg (static)
      compute(cur * ABYTES, seg * SPS + sub);
      __syncthreads();            // drains A prefetch + closes LDS read window
      cur ^= 1;
    }
  }

  // epilogue: C/D layout col=lane&15, row=(lane>>4)*4+reg (m89-verified)
  const int colb = wc * 64 + (l & 15);
  const int rowb = m0 + wr * 64 + ((l >> 4) << 2);
  #pragma unroll
  for (int mf = 0; mf < 4; ++mf) {
    #pragma unroll
    for (int nf = 0; nf < 4; ++nf) {
      f32x4 d = acc[mf][nf];
      #pragma unroll
      for (int r = 0; r < 4; ++r) {
        float v = tanhf(d[r]);
        size_t o = (size_t)(rowb + mf * 16 + r) * DD + colb + nf * 16;
        unsigned short hv16 = f2h(v);
        ob[o] = hv16;
        if (ob2) ob2[o] = hv16;
        if (of)  of[o]  = v;
      }
    }
  }
}

// -------------------------- helper kernels ---------------------------------

__global__ __launch_bounds__(256)
void f32_to_f16(const float* __restrict__ in, ushort_t* __restrict__ out, int n4) {
  int t = blockIdx.x * 256 + threadIdx.x;
  if (t >= n4) return;
  float4 v = ((const float4*)in)[t];
  ushort4 o; o.x = f2h(v.x); o.y = f2h(v.y); o.z = f2h(v.z); o.w = f2h(v.w);
  ((ushort4*)out)[t] = o;
}

// W [K][256] f32 -> PreW fragment-major f16 (see GEMM header comment).
// q = 16B chunk index; total 1024*KTOT chunks.
__global__ __launch_bounds__(256)
void prew_transform(const float* __restrict__ in, ushort_t* __restrict__ out, int KTOT) {
  int q = blockIdx.x * 256 + threadIdx.x;
  int c  = q & 15;
  int kc = (q >> 4) & 3;
  int kt = (q >> 6) % KTOT;
  int g  = (q >> 6) / KTOT;
  int col = g * 16 + c;
  int k0  = kt * 32 + kc * 8;
  ushort_t* o = out + (size_t)q * 8;
  #pragma unroll
  for (int j = 0; j < 8; ++j)
    o[j] = f2h(in[(size_t)(k0 + j) * DD + col]);
}

__global__ __launch_bounds__(256)
void init_he0_k(const float* __restrict__ bo, const float* __restrict__ wfe,
                ushort_t* __restrict__ he0, ushort_t* __restrict__ he) {
  int t = blockIdx.x * 256 + threadIdx.x;   // N_BONDS*64
  int b = t >> 6, c = (t & 63) << 2;
  float o = bo[b];
  float4 w = *(const float4*)&wfe[c];
  ushort4 v;
  v.x = f2h(tanhf(o * w.x)); v.y = f2h(tanhf(o * w.y));
  v.z = f2h(tanhf(o * w.z)); v.w = f2h(tanhf(o * w.w));
  size_t idx = ((size_t)b * DD + c) >> 2;
  ((ushort4*)he0)[idx] = v; ((ushort4*)he)[idx] = v;
}

// msum[mol] += atoms[a], cnt[mol] += 1 -- SORTED atom_mol: run-compress.
__global__ __launch_bounds__(128)
void mol_accum_sorted(const float* __restrict__ atoms, const int* __restrict__ amol,
                      float* __restrict__ msum, float* __restrict__ cnt) {
  __shared__ int sid[64];
  int r0 = blockIdx.x * 64;
  int c  = threadIdx.x;                     // 128 threads = 128 cols
  if (c < 64) sid[c] = amol[r0 + c];
  __syncthreads();
  float acc = 0.f; int prev = sid[0]; int run = 0;
  const float* p = atoms + (size_t)r0 * D_IN + c;
  for (int r = 0; r < 64; ++r, p += D_IN) {
    int id = sid[r];                        // wave-uniform
    if (id != prev) {
      unsafeAtomicAdd(&msum[(size_t)prev * D_IN + c], acc);
      if (c == 0) unsafeAtomicAdd(&cnt[prev], (float)run);
      acc = 0.f; run = 0; prev = id;
    }
    acc += *p; run += 1;
  }
  unsafeAtomicAdd(&msum[(size_t)prev * D_IN + c], acc);
  if (c == 0) unsafeAtomicAdd(&cnt[prev], (float)run);
}

__global__ __launch_bounds__(256)
void mol_mean_h(const float* __restrict__ msum, const float* __restrict__ cnt,
                ushort_t* __restrict__ mmean) {
  int t = blockIdx.x * 256 + threadIdx.x;   // N_MOLS*32
  int m = t >> 5, c = (t & 31) << 2;
  float inv = 1.0f / fmaxf(cnt[m], 1.0f);
  float4 v = *(const float4*)&msum[(size_t)m * D_IN + c];
  ushort4 o; o.x = f2h(v.x * inv); o.y = f2h(v.y * inv);
  o.z = f2h(v.z * inv); o.w = f2h(v.w * inv);
  ((ushort4*)mmean)[((size_t)m * D_IN + c) >> 2] = o;
}

// ---- CSR incidence build (bond endpoints are static per call) -------------

__global__ __launch_bounds__(256)
void count_deg(const int* __restrict__ src, const int* __restrict__ dst,
               int* __restrict__ deg) {
  int b = blockIdx.x * 256 + threadIdx.x;
  if (b >= N_BONDS) return;
  atomicAdd(&deg[src[b]], 1);
  atomicAdd(&deg[dst[b]], 1);
}

__global__ __launch_bounds__(256)
void scan_deg(const int* __restrict__ deg, int* __restrict__ rowptr,
              int* __restrict__ cursor) {
  __shared__ int partial[256];
  int t = threadIdx.x;
  int base = t * 256;
  int s = 0;
  for (int i = 0; i < 256; ++i) s += deg[base + i];
  partial[t] = s;
  __syncthreads();
  if (t == 0) {
    int acc = 0;
    for (int i = 0; i < 256; ++i) { int v = partial[i]; partial[i] = acc; acc += v; }
    rowptr[N_ATOMS] = acc;
  }
  __syncthreads();
  int acc = partial[t];
  for (int i = 0; i < 256; ++i) {
    rowptr[base + i] = acc; cursor[base + i] = acc;
    acc += deg[base + i];
  }
}

__global__ __launch_bounds__(256)
void fill_csr(const int* __restrict__ src, const int* __restrict__ dst,
              int* __restrict__ cursor, int* __restrict__ list) {
  int b = blockIdx.x * 256 + threadIdx.x;
  if (b >= N_BONDS) return;
  int p = atomicAdd(&cursor[src[b]], 1); list[p] = b;
  int q = atomicAdd(&cursor[dst[b]], 1); list[q] = b;
}

// e_bar_v[a] = sum_{b in inc(a)} h_e[b]; one wave per atom (uniform loop).
__global__ __launch_bounds__(256)
void gather_ebv(const ushort_t* __restrict__ he, const int* __restrict__ rowptr,
                const int* __restrict__ list, ushort_t* __restrict__ ebv_h) {
  int t = blockIdx.x * 256 + threadIdx.x;   // N_ATOMS*64 threads
  int a = t >> 6, c = (t & 63) << 2;
  int s = rowptr[a], e = rowptr[a + 1];
  float a0 = 0.f, a1 = 0.f, a2 = 0.f, a3 = 0.f;
  for (int i = s; i < e; ++i) {
    int b = list[i];                        // wave-uniform broadcast
    ushort4 v = *(const ushort4*)&he[(size_t)b * DD + c];
    a0 += h2f(v.x); a1 += h2f(v.y); a2 += h2f(v.z); a3 += h2f(v.w);
  }
  ushort4 o; o.x = f2h(a0); o.y = f2h(a1); o.z = f2h(a2); o.w = f2h(a3);
  ((ushort4*)ebv_h)[((size_t)a * DD + c) >> 2] = o;
}

// out[ids[r]] += x[r] for SORTED ids: run-compress in registers.
__global__ __launch_bounds__(256)
void seg_sum_sorted(const ushort_t* __restrict__ x, const int* __restrict__ ids,
                    float* __restrict__ out) {
  __shared__ int sid[64];
  int r0 = blockIdx.x * 64;
  int c  = threadIdx.x;                     // 256 threads = 256 cols
  if (c < 64) sid[c] = ids[r0 + c];
  __syncthreads();
  float acc = 0.f; int prev = sid[0];
  const ushort_t* p = x + (size_t)r0 * DD + c;
  for (int r = 0; r < 64; ++r, p += DD) {
    int id = sid[r];                        // wave-uniform
    if (id != prev) { unsafeAtomicAdd(&out[(size_t)prev * DD + c], acc); acc = 0.f; prev = id; }
    acc += h2f(*p);
  }
  unsafeAtomicAdd(&out[(size_t)prev * DD + c], acc);
}

// ---------------------------------------------------------------------------

extern "C" void kernel_launch(void* const* d_in, const int* in_sizes, int n_in,
                              void* d_out, int out_size, void* d_ws, size_t ws_size,
                              hipStream_t stream)
{
  const float* atoms       = (const float*)d_in[0];
  const float* bond_orders = (const float*)d_in[1];
  const int*   bond_src    = (const int*)d_in[2];
  const int*   bond_dst    = (const int*)d_in[3];
  const int*   atom_mol    = (const int*)d_in[4];
  const int*   bond_mol    = (const int*)d_in[5];
  const float* W_fe        = (const float*)d_in[6];
  const float* W_fv        = (const float*)d_in[7];
  const float* W_fu        = (const float*)d_in[8];
  const float* W_e         = (const float*)d_in[9];
  const float* W_v         = (const float*)d_in[10];
  const float* W_u         = (const float*)d_in[11];

  char* w = (char*)d_ws;
  auto alloc = [&](size_t bytes) { char* p = w; w += (bytes + 255) & ~(size_t)255; return p; };

  ushort_t* atoms_h  = (ushort_t*)alloc((size_t)N_ATOMS * D_IN * 2);
  ushort_t* he0  = (ushort_t*)alloc((size_t)N_BONDS * DD * 2);
  ushort_t* he   = (ushort_t*)alloc((size_t)N_BONDS * DD * 2);
  ushort_t* hv0  = (ushort_t*)alloc((size_t)N_ATOMS * DD * 2);
  ushort_t* hv   = (ushort_t*)alloc((size_t)N_ATOMS * DD * 2);
  ushort_t* hu0  = (ushort_t*)alloc((size_t)N_MOLS * DD * 2);
  ushort_t* hu   = (ushort_t*)alloc((size_t)N_MOLS * DD * 2);
  ushort_t* mmean= (ushort_t*)alloc((size_t)N_MOLS * D_IN * 2);
  ushort_t* PWe  = (ushort_t*)alloc((size_t)DD * 1280 * 2);
  ushort_t* PWv  = (ushort_t*)alloc((size_t)DD * 1024 * 2);
  ushort_t* PWu  = (ushort_t*)alloc((size_t)DD * 1024 * 2);
  ushort_t* PWfv = (ushort_t*)alloc((size_t)DD * D_IN * 2);
  ushort_t* PWfu = (ushort_t*)alloc((size_t)DD * D_IN * 2);
  float* eb_f  = (float*)alloc((size_t)N_MOLS * DD * 4);        // eb,vb contiguous
  float* vb_f  = (float*)alloc((size_t)N_MOLS * DD * 4);
  ushort_t* ebv_h = (ushort_t*)alloc((size_t)N_ATOMS * DD * 2);
  ushort_t* eb_h  = (ushort_t*)alloc((size_t)N_MOLS * DD * 2);  // eb_h,vb_h contiguous
  ushort_t* vb_h  = (ushort_t*)alloc((size_t)N_MOLS * DD * 2);
  float* msum = (float*)alloc((size_t)N_MOLS * D_IN * 4);       // msum,cnt contiguous
  float* cnt  = (float*)alloc((size_t)N_MOLS * 4);
  int* deg    = (int*)alloc((size_t)N_ATOMS * 4);
  int* rowptr = (int*)alloc((size_t)(N_ATOMS + 1) * 4);
  int* cursor = (int*)alloc((size_t)N_ATOMS * 4);
  int* list   = (int*)alloc((size_t)2 * N_BONDS * 4);
  if ((size_t)(w - (char*)d_ws) > ws_size) return;

  const ushort_t* NU = nullptr; const int* NI = nullptr;

  // ---- one-time converts (fragment-major weights) + CSR build ----
  f32_to_f16<<<N_ATOMS * D_IN / 4 / 256, 256, 0, stream>>>(atoms, atoms_h, N_ATOMS * D_IN / 4);
  prew_transform<<<4 * 40, 256, 0, stream>>>(W_e, PWe, 40);
  prew_transform<<<4 * 32, 256, 0, stream>>>(W_v, PWv, 32);
  prew_transform<<<4 * 32, 256, 0, stream>>>(W_u, PWu, 32);
  prew_transform<<<4 * 4,  256, 0, stream>>>(W_fv, PWfv, 4);
  prew_transform<<<4 * 4,  256, 0, stream>>>(W_fu, PWfu, 4);
  hipMemsetAsync(deg, 0, (size_t)N_ATOMS * 4, stream);
  count_deg<<<(N_BONDS + 255) / 256, 256, 0, stream>>>(bond_src, bond_dst, deg);
  scan_deg<<<1, 256, 0, stream>>>(deg, rowptr, cursor);
  fill_csr<<<(N_BONDS + 255) / 256, 256, 0, stream>>>(bond_src, bond_dst, cursor, list);

  // ---- init embeddings ----
  hipMemsetAsync(msum, 0, (size_t)(N_MOLS * D_IN + N_MOLS) * 4, stream);
  mol_accum_sorted<<<N_ATOMS / 64, 128, 0, stream>>>(atoms, atom_mol, msum, cnt);
  mol_mean_h<<<N_MOLS * 32 / 256, 256, 0, stream>>>(msum, cnt, mmean);
  init_he0_k<<<N_BONDS * 64 / 256, 256, 0, stream>>>(bond_orders, W_fe, he0, he);
  mfma_concat_gemm<1, 128, 128><<<N_ATOMS / 128, 512, 0, stream>>>(
      atoms_h, NI, NU, NI, NU, NI, NU, NI, NU, NI, PWfv, hv0, hv, nullptr);
  mfma_concat_gemm<1, 128, 64><<<N_MOLS / 64, 256, 0, stream>>>(
      mmean, NI, NU, NI, NU, NI, NU, NI, NU, NI, PWfu, hu0, hu, nullptr);

  // ---- 3 message-passing iterations (all h updates in-place, full-N blocks) ----
  for (int it = 0; it < REPEAT; ++it) {
    hipMemsetAsync(eb_f, 0, (size_t)2 * N_MOLS * DD * 4, stream);
    mfma_concat_gemm<5, 256, 128><<<N_BONDS / 128, 512, 0, stream>>>(
        he, NI, he0, NI, hv, bond_src, hv, bond_dst, hu, bond_mol,
        PWe, he, nullptr, it == REPEAT - 1 ? (float*)d_out : nullptr);
    gather_ebv<<<N_ATOMS * 64 / 256, 256, 0, stream>>>(he, rowptr, list, ebv_h);
    seg_sum_sorted<<<N_BONDS / 64, 256, 0, stream>>>(he, bond_mol, eb_f);
    mfma_concat_gemm<4, 256, 128><<<N_ATOMS / 128, 512, 0, stream>>>(
        hv, NI, hv0, NI, ebv_h, NI, hu, atom_mol, NU, NI,
        PWv, hv, nullptr, nullptr);
    seg_sum_sorted<<<N_ATOMS / 64, 256, 0, stream>>>(hv, atom_mol, vb_f);
    f32_to_f16<<<2 * N_MOLS * DD / 4 / 256, 256, 0, stream>>>(eb_f, eb_h, 2 * N_MOLS * DD / 4);
    mfma_concat_gemm<4, 256, 64><<<N_MOLS / 64, 256, 0, stream>>>(
        hu, NI, hu0, NI, eb_h, NI, vb_h, NI, NU, NI,
        PWu, hu, nullptr, nullptr);
  }
}